// Round 7
// baseline (992.957 us; speedup 1.0000x reference)
//
#include <hip/hip_runtime.h>
#include <cstddef>

#define D 64
#define K 512
#define NROWS (32*64*64)       // 131072 rows
#define RPB 64                 // rows per block (vq_main)
#define NBLK (NROWS / RPB)     // 2048 blocks
#define NOUT 8388608           // NROWS * D

// ws layout (floats):
//   [0,      32768)  : eT[K][D]     plain transposed codebook (epilogue gather)
//   [32768,  65536)  : eP[K][4][16] permuted: eP[k][m][j] = emb[(4j+m)*K + k]
//   [65536,  66048)  : enorm[K]     (np-rounding-exact sequential non-fused sum)
//   [66048]          : loss sum accumulator (float, atomicAdd)
//   [66049]          : done-block counter (uint)

__global__ __launch_bounds__(256) void vq_prep(const float* __restrict__ emb,
                                               float* __restrict__ eT,
                                               float* __restrict__ eP,
                                               float* __restrict__ enorm,
                                               float* __restrict__ lsum,
                                               unsigned* __restrict__ done) {
    const int k = blockIdx.x * blockDim.x + threadIdx.x;
    if (k == 0) { *lsum = 0.f; *done = 0u; }   // ws is 0xAA-poisoned every launch
    if (k >= K) return;
    // np.sum(emb*emb, axis=0): sequential row sweep over individually-rounded
    // products (no FMA contraction) — bit-exact vs np reference (r2-r6 proven).
    float nrm = 0.f;
#pragma unroll
    for (int d = 0; d < D; ++d) {
        const float v = emb[d * K + k];        // coalesced across k
        nrm = __fadd_rn(nrm, __fmul_rn(v, v));
        eT[k * D + d] = v;
        eP[k * D + (d & 3) * 16 + (d >> 2)] = v;   // [k][m][j], d = 4j+m
    }
    enorm[k] = nrm;
}

// Round-7 structure (post-mortems r2-r6): the allocator always targets the
// 64-VGPR / 8-waves-per-EU budget and spills anything bigger, and lgkmcnt
// mixing (ds_read x + s_load e) serializes the r6 loop. Fix: 4 lanes per row,
// lane m holds ONLY xq[j]=x[4j+m] (16 loop-invariant regs -> fits the budget
// by construction), computes the verified chain a_m, and the verified combine
// tree ((a0+a1)+(a2+a3)) is realized with two commutative __shfl_xor adds
// (bitwise-identical fp results). e comes from eP via per-lane 16B vector
// loads (coalesced 256B/wave, L1/L2-hot, vmcnt-pipelined). 8 waves/SIMD of
// TLP hides all remaining latency.
__global__ __launch_bounds__(256) void vq_main(const float* __restrict__ x,
                                               const float* __restrict__ eT,
                                               const float* __restrict__ eP,
                                               const float* __restrict__ enorm,
                                               float* __restrict__ out,
                                               float* __restrict__ lsum,
                                               unsigned* __restrict__ done) {
    __shared__ float xT[D][RPB];     // 16 KB transposed x tile (dead after scan setup)
    __shared__ float s_en[K];        // 2 KB
    __shared__ int   s_code[RPB];
    __shared__ float s_red[4];

    const int t    = threadIdx.x;
    const int wave = t >> 6;
    const int lane = t & 63;
    const int m    = lane & 3;       // dim-residue owned by this lane
    const int quad = lane >> 2;      // 16 quads per wave
    const int lrow = (wave << 4) + quad;   // local row 0..63
    const size_t rowbase = (size_t)blockIdx.x * RPB;

    // ---- stage x tile into LDS transposed (r6-verified pattern; lane = row) ----
    {
        const float4* __restrict__ src = (const float4*)(x + (rowbase + lane) * D + wave * 16);
        const float4 v0 = src[0], v1 = src[1], v2 = src[2], v3 = src[3];
        const int d0 = wave * 16;
        xT[d0+ 0][lane] = v0.x; xT[d0+ 1][lane] = v0.y; xT[d0+ 2][lane] = v0.z; xT[d0+ 3][lane] = v0.w;
        xT[d0+ 4][lane] = v1.x; xT[d0+ 5][lane] = v1.y; xT[d0+ 6][lane] = v1.z; xT[d0+ 7][lane] = v1.w;
        xT[d0+ 8][lane] = v2.x; xT[d0+ 9][lane] = v2.y; xT[d0+10][lane] = v2.z; xT[d0+11][lane] = v2.w;
        xT[d0+12][lane] = v3.x; xT[d0+13][lane] = v3.y; xT[d0+14][lane] = v3.z; xT[d0+15][lane] = v3.w;
    }
    s_en[t] = enorm[t];
    s_en[t + 256] = enorm[t + 256];
    __syncthreads();

    // ---- xnorm of row lrow: exact numpy pairwise tree (r6-verified code) ----
    // All 4 lanes of a quad compute it redundantly (same-addr LDS broadcast).
    float r0, r1, r2, r3, r4, r5, r6, r7;
    {
        float v;
        v = xT[0][lrow]; r0 = __fmul_rn(v, v);
        v = xT[1][lrow]; r1 = __fmul_rn(v, v);
        v = xT[2][lrow]; r2 = __fmul_rn(v, v);
        v = xT[3][lrow]; r3 = __fmul_rn(v, v);
        v = xT[4][lrow]; r4 = __fmul_rn(v, v);
        v = xT[5][lrow]; r5 = __fmul_rn(v, v);
        v = xT[6][lrow]; r6 = __fmul_rn(v, v);
        v = xT[7][lrow]; r7 = __fmul_rn(v, v);
#pragma unroll
        for (int b = 1; b < 8; ++b) {
            v = xT[8*b+0][lrow]; r0 = __fadd_rn(r0, __fmul_rn(v, v));
            v = xT[8*b+1][lrow]; r1 = __fadd_rn(r1, __fmul_rn(v, v));
            v = xT[8*b+2][lrow]; r2 = __fadd_rn(r2, __fmul_rn(v, v));
            v = xT[8*b+3][lrow]; r3 = __fadd_rn(r3, __fmul_rn(v, v));
            v = xT[8*b+4][lrow]; r4 = __fadd_rn(r4, __fmul_rn(v, v));
            v = xT[8*b+5][lrow]; r5 = __fadd_rn(r5, __fmul_rn(v, v));
            v = xT[8*b+6][lrow]; r6 = __fadd_rn(r6, __fmul_rn(v, v));
            v = xT[8*b+7][lrow]; r7 = __fadd_rn(r7, __fmul_rn(v, v));
        }
    }
    const float xnorm = __fadd_rn(__fadd_rn(__fadd_rn(r0, r1), __fadd_rn(r2, r3)),
                                  __fadd_rn(__fadd_rn(r4, r5), __fadd_rn(r6, r7)));

    // ---- this lane's x fragment: xq[j] = x[4j+m] (16 loop-invariant regs) ----
    float xq[16];
#pragma unroll
    for (int j = 0; j < 16; ++j) xq[j] = xT[4*j + m][lrow];

    // ---- scan ALL 512 codes, 4 per group; lane m ends owning code k0+m ----
    // Chain m of code c: acc = sum_j xq[j]*eP[c][m][j], j ascending, 16 deep —
    // bit-identical to the verified r2/r3/r5/r6 chains. Combine across the
    // quad with 2 commutative shfl_xor adds = ((a0+a1)+(a2+a3)) exactly.
    float best = 3.4028235e38f;
    int   bidx = 0;
    const float* __restrict__ ebase = eP + m * 16;
#pragma unroll 1
    for (int g = 0; g < 128; ++g) {
        const int k0 = g << 2;
        const float* __restrict__ bp = ebase + ((size_t)k0 << 6);  // + k0*64 floats
        float a0 = 0.f, a1 = 0.f, a2 = 0.f, a3 = 0.f;
#pragma unroll
        for (int u = 0; u < 4; ++u) {
            const float4 e0 = *(const float4*)(bp +   0 + 4*u);
            const float4 e1 = *(const float4*)(bp +  64 + 4*u);
            const float4 e2 = *(const float4*)(bp + 128 + 4*u);
            const float4 e3 = *(const float4*)(bp + 192 + 4*u);
            const float xa = xq[4*u+0], xb = xq[4*u+1], xc = xq[4*u+2], xd = xq[4*u+3];
            a0 = fmaf(xa, e0.x, a0); a1 = fmaf(xa, e1.x, a1); a2 = fmaf(xa, e2.x, a2); a3 = fmaf(xa, e3.x, a3);
            a0 = fmaf(xb, e0.y, a0); a1 = fmaf(xb, e1.y, a1); a2 = fmaf(xb, e2.y, a2); a3 = fmaf(xb, e3.y, a3);
            a0 = fmaf(xc, e0.z, a0); a1 = fmaf(xc, e1.z, a1); a2 = fmaf(xc, e2.z, a2); a3 = fmaf(xc, e3.z, a3);
            a0 = fmaf(xd, e0.w, a0); a1 = fmaf(xd, e1.w, a1); a2 = fmaf(xd, e2.w, a2); a3 = fmaf(xd, e3.w, a3);
        }
        // combine: step1 pairs (xor 1) then step2 (xor 2); fp add is exactly
        // commutative, so every lane holds the verified ((a0+a1)+(a2+a3)).
        float d0t = __fadd_rn(a0, __shfl_xor(a0, 1)); d0t = __fadd_rn(d0t, __shfl_xor(d0t, 2));
        float d1t = __fadd_rn(a1, __shfl_xor(a1, 1)); d1t = __fadd_rn(d1t, __shfl_xor(d1t, 2));
        float d2t = __fadd_rn(a2, __shfl_xor(a2, 1)); d2t = __fadd_rn(d2t, __shfl_xor(d2t, 2));
        float d3t = __fadd_rn(a3, __shfl_xor(a3, 1)); d3t = __fadd_rn(d3t, __shfl_xor(d3t, 2));
        // lane m takes code k0+m
        float dot = (m == 0) ? d0t : (m == 1) ? d1t : (m == 2) ? d2t : d3t;
        const float dd = __fadd_rn(__fsub_rn(xnorm, __fmul_rn(2.f, dot)), s_en[k0 + m]);
        // ascending k within this lane's subset; strict < keeps first minimum
        if (dd < best) { best = dd; bidx = k0 + m; }
    }

    // ---- per-row argmin across the quad (full index tie-break: subsets interleave) ----
    {
        float ob = __shfl_xor(best, 1); int oi = __shfl_xor(bidx, 1);
        if (ob < best || (ob == best && oi < bidx)) { best = ob; bidx = oi; }
        ob = __shfl_xor(best, 2); oi = __shfl_xor(bidx, 2);
        if (ob < best || (ob == best && oi < bidx)) { best = ob; bidx = oi; }
    }
    if (m == 0) s_code[lrow] = bidx;
    __syncthreads();

    // ---- coalesced transpose epilogue (r6-verified): 16 lanes per row ----
    const int c   = t & 15;      // float4 chunk within row
    const int r0i = t >> 4;      // base row 0..15
    float lacc = 0.f;
#pragma unroll
    for (int i = 0; i < 4; ++i) {
        const int r = r0i + 16 * i;
        const int code = s_code[r];
        const float4 q = *(const float4*)(eT + (size_t)code * D + 4 * c);
        const float4 b = *(const float4*)(x + (rowbase + r) * D + 4 * c);
        const float f0 = __fsub_rn(b.x, q.x), f1 = __fsub_rn(b.y, q.y);
        const float f2 = __fsub_rn(b.z, q.z), f3 = __fsub_rn(b.w, q.w);
        lacc = fmaf(f0, f0, lacc); lacc = fmaf(f1, f1, lacc);
        lacc = fmaf(f2, f2, lacc); lacc = fmaf(f3, f3, lacc);
        float4 o;
        o.x = __fadd_rn(b.x, __fsub_rn(q.x, b.x));
        o.y = __fadd_rn(b.y, __fsub_rn(q.y, b.y));
        o.z = __fadd_rn(b.z, __fsub_rn(q.z, b.z));
        o.w = __fadd_rn(b.w, __fsub_rn(q.w, b.w));
        *(float4*)(out + (rowbase + r) * D + 4 * c) = o;
    }

    // ---- block loss partial + fused finish (last block writes the scalar) ----
#pragma unroll
    for (int off = 32; off > 0; off >>= 1) lacc += __shfl_down(lacc, off);
    if (lane == 0) s_red[wave] = lacc;
    __syncthreads();
    if (t == 0) {
        const float part = (s_red[0] + s_red[1]) + (s_red[2] + s_red[3]);
        atomicAdd(lsum, part);                       // device-scope by default
        __threadfence();
        const unsigned prev = atomicAdd(done, 1u);
        if (prev == NBLK - 1) {                      // all partials are in
            const float total = atomicAdd(lsum, 0.f);   // atomic read-back
            const float mm = total / (float)NOUT;
            out[NOUT] = mm + 0.25f * mm;             // mean + BETA*mean
        }
    }
}

extern "C" void kernel_launch(void* const* d_in, const int* in_sizes, int n_in,
                              void* d_out, int out_size, void* d_ws, size_t ws_size,
                              hipStream_t stream) {
    const float* x   = (const float*)d_in[0];
    const float* emb = (const float*)d_in[1];
    float* out = (float*)d_out;
    float* ws  = (float*)d_ws;

    float*    eT    = ws;
    float*    eP    = ws + 32768;
    float*    enorm = ws + 65536;
    float*    lsum  = ws + 66048;
    unsigned* done  = (unsigned*)(ws + 66049);

    vq_prep<<<2, 256, 0, stream>>>(emb, eT, eP, enorm, lsum, done);
    vq_main<<<NBLK, 256, 0, stream>>>(x, eT, eP, enorm, out, lsum, done);
}